// Round 1
// baseline (853.268 us; speedup 1.0000x reference)
//
#include <hip/hip_runtime.h>
#include <cstdint>
#include <cstddef>

// Problem constants
// x: [512][64][1024], conv1: K=32 S=16 -> T=63, Cout=256
// z1/z2 layout: [n][t][c] flat = (n*63+t)*256 + c   (== GEMM C row-major)

// ---------------------------------------------------------------------------
// K0: prep — fold BN into alpha/beta, transpose w1 -> w1T[c][o],
//     transpose conv2_w -> w2cT[(dt*256+c)*256 + o]
// ---------------------------------------------------------------------------
__global__ __launch_bounds__(256) void prep_kernel(
    const float* __restrict__ c1b, const float* __restrict__ g1,
    const float* __restrict__ b1,  const float* __restrict__ m1,
    const float* __restrict__ v1,
    const float* __restrict__ c2w, const float* __restrict__ c2b,
    const float* __restrict__ g2,  const float* __restrict__ b2,
    const float* __restrict__ m2,  const float* __restrict__ v2,
    const float* __restrict__ w1,
    float* __restrict__ w1T, float* __restrict__ w2cT,
    float* __restrict__ ab1, float* __restrict__ ab2)
{
    const int id = blockIdx.x * 256 + threadIdx.x;   // 65536 total
    if (id < 256) {
        float a1 = g1[id] / sqrtf(v1[id] + 1e-5f);
        ab1[id]       = a1;
        ab1[256 + id] = (c1b[id] - m1[id]) * a1 + b1[id];
        float a2 = g2[id] / sqrtf(v2[id] + 1e-5f);
        ab2[id]       = a2;
        ab2[256 + id] = (c2b[id] - m2[id]) * a2 + b2[id];
    }
    {   // w1T[c*256+o] = w1[o*256+c]
        const int c = id >> 8, o = id & 255;
        w1T[id] = w1[o * 256 + c];
    }
    for (int idx = id; idx < 3 * 256 * 256; idx += 65536) {
        const int o   = idx & 255;
        const int kap = idx >> 8;      // dt*256 + c
        const int dt  = kap >> 8;
        const int c   = kap & 255;
        w2cT[idx] = c2w[o * 768 + c * 3 + dt];
    }
}

// ---------------------------------------------------------------------------
// K1: conv1 + bn1 as tiled fp32 GEMM.  M=32256 (n,t), K=2048 (c*32+k), N=256 (o)
// Tile 128x128x16, 256 threads, 8x8 per thread.
// ---------------------------------------------------------------------------
__global__ __launch_bounds__(256) void conv1_gemm(
    const float* __restrict__ x, const float* __restrict__ w1c,
    const float* __restrict__ ab, float* __restrict__ z1)
{
    __shared__ float As[16][128];
    __shared__ float Bs[16][128];
    const int tid = threadIdx.x;
    const int bm  = blockIdx.x;        // 0..251
    const int bn  = blockIdx.y;        // 0..1

    // loader mapping: row = tid&127, k-quad = tid>>7 (and +2)
    const int lr  = tid & 127;
    const int lkq = tid >> 7;
    const int am  = bm * 128 + lr;
    const int an  = am / 63;
    const int at  = am - an * 63;
    const float* arow = x + (size_t)an * 65536 + at * 16;   // + c0*1024 + k
    const float* brow = w1c + (size_t)(bn * 128 + lr) * 2048;

    const int tx = tid & 15, ty = tid >> 4;
    float acc[8][8] = {};

    for (int it = 0; it < 128; ++it) {
        const int kap0 = it * 16;
        const int aoff = (kap0 >> 5) * 1024 + (kap0 & 31);  // c0*1024 + k0
        const int boff = (kap0 >> 5) * 32   + (kap0 & 31);  // c0*32 + k0
#pragma unroll
        for (int q = 0; q < 2; ++q) {
            const int kq = lkq + 2 * q;
            float4 av = *(const float4*)(arow + aoff + kq * 4);
            As[kq*4+0][lr] = av.x; As[kq*4+1][lr] = av.y;
            As[kq*4+2][lr] = av.z; As[kq*4+3][lr] = av.w;
            float4 bv = *(const float4*)(brow + boff + kq * 4);
            Bs[kq*4+0][lr] = bv.x; Bs[kq*4+1][lr] = bv.y;
            Bs[kq*4+2][lr] = bv.z; Bs[kq*4+3][lr] = bv.w;
        }
        __syncthreads();
#pragma unroll
        for (int k = 0; k < 16; ++k) {
            float a[8], b[8];
            *(float4*)&a[0] = *(const float4*)&As[k][tx*8];
            *(float4*)&a[4] = *(const float4*)&As[k][tx*8+4];
            *(float4*)&b[0] = *(const float4*)&Bs[k][ty*8];
            *(float4*)&b[4] = *(const float4*)&Bs[k][ty*8+4];
#pragma unroll
            for (int i = 0; i < 8; ++i)
#pragma unroll
                for (int j = 0; j < 8; ++j)
                    acc[i][j] += a[i] * b[j];
        }
        __syncthreads();
    }
    const int gm0 = bm * 128 + tx * 8;
    const int go0 = bn * 128 + ty * 8;
    float al[8], be[8];
#pragma unroll
    for (int j = 0; j < 8; ++j) { al[j] = ab[go0+j]; be[j] = ab[256+go0+j]; }
#pragma unroll
    for (int i = 0; i < 8; ++i) {
        float4 v0, v1;
        v0.x = acc[i][0]*al[0]+be[0]; v0.y = acc[i][1]*al[1]+be[1];
        v0.z = acc[i][2]*al[2]+be[2]; v0.w = acc[i][3]*al[3]+be[3];
        v1.x = acc[i][4]*al[4]+be[4]; v1.y = acc[i][5]*al[5]+be[5];
        v1.z = acc[i][6]*al[6]+be[6]; v1.w = acc[i][7]*al[7]+be[7];
        float* p = z1 + (size_t)(gm0 + i) * 256 + go0;
        *(float4*)p       = v0;
        *(float4*)(p + 4) = v1;
    }
}

// ---------------------------------------------------------------------------
// K2: conv2 + bn2 as tiled fp32 GEMM.  K=768 (dt*256+c), zero-padded halo in t.
// ---------------------------------------------------------------------------
__global__ __launch_bounds__(256) void conv2_gemm(
    const float* __restrict__ z1, const float* __restrict__ w2cT,
    const float* __restrict__ ab, float* __restrict__ z2)
{
    __shared__ float As[16][128];
    __shared__ float Bs[16][128];
    const int tid = threadIdx.x;
    const int bm  = blockIdx.x;
    const int bn  = blockIdx.y;

    const int lr  = tid & 127;
    const int lkq = tid >> 7;
    const int am  = bm * 128 + lr;
    const int an  = am / 63;
    const int at  = am - an * 63;
    const float* abase = z1 + (size_t)an * 16128;

    const int boq = tid & 31;          // o-quad 0..31
    const int bk  = tid >> 5;          // 0..7 (k and k+8)
    const int go0b = bn * 128 + boq * 4;

    const int tx = tid & 15, ty = tid >> 4;
    float acc[8][8] = {};

    for (int it = 0; it < 48; ++it) {
        const int kap0 = it * 16;
        const int dt   = kap0 >> 8;    // 0..2
        const int c0   = kap0 & 255;
        const int trow = at + dt - 1;
        const bool valid = (trow >= 0) && (trow < 63);
        const float* arow = abase + trow * 256 + c0;
#pragma unroll
        for (int q = 0; q < 2; ++q) {
            const int kq = lkq + 2 * q;
            float4 av = make_float4(0.f, 0.f, 0.f, 0.f);
            if (valid) av = *(const float4*)(arow + kq * 4);
            As[kq*4+0][lr] = av.x; As[kq*4+1][lr] = av.y;
            As[kq*4+2][lr] = av.z; As[kq*4+3][lr] = av.w;
            const int kk = bk + 8 * q;
            float4 bv = *(const float4*)(w2cT + (size_t)(kap0 + kk) * 256 + go0b);
            *(float4*)&Bs[kk][boq * 4] = bv;
        }
        __syncthreads();
#pragma unroll
        for (int k = 0; k < 16; ++k) {
            float a[8], b[8];
            *(float4*)&a[0] = *(const float4*)&As[k][tx*8];
            *(float4*)&a[4] = *(const float4*)&As[k][tx*8+4];
            *(float4*)&b[0] = *(const float4*)&Bs[k][ty*8];
            *(float4*)&b[4] = *(const float4*)&Bs[k][ty*8+4];
#pragma unroll
            for (int i = 0; i < 8; ++i)
#pragma unroll
                for (int j = 0; j < 8; ++j)
                    acc[i][j] += a[i] * b[j];
        }
        __syncthreads();
    }
    const int gm0 = bm * 128 + tx * 8;
    const int go0 = bn * 128 + ty * 8;
    float al[8], be[8];
#pragma unroll
    for (int j = 0; j < 8; ++j) { al[j] = ab[go0+j]; be[j] = ab[256+go0+j]; }
#pragma unroll
    for (int i = 0; i < 8; ++i) {
        float4 v0, v1;
        v0.x = acc[i][0]*al[0]+be[0]; v0.y = acc[i][1]*al[1]+be[1];
        v0.z = acc[i][2]*al[2]+be[2]; v0.w = acc[i][3]*al[3]+be[3];
        v1.x = acc[i][4]*al[4]+be[4]; v1.y = acc[i][5]*al[5]+be[5];
        v1.z = acc[i][6]*al[6]+be[6]; v1.w = acc[i][7]*al[7]+be[7];
        float* p = z2 + (size_t)(gm0 + i) * 256 + go0;
        *(float4*)p       = v0;
        *(float4*)(p + 4) = v1;
    }
}

// ---------------------------------------------------------------------------
// K3: fused SNN tail, one block per n (256 threads):
//   phase1: cuba1 (thr=channel, thr=0.3, cd=vd=0.1) -> 63-bit spike mask/reg
//   phase2: dense1 (w1T) + cuba2 (thr=0.1, i=x, v=0.9v+x), 4 chunks of 16 t,
//           spikes expanded to LDS floats per chunk (broadcast b128 reads)
//   phase3: dense2 (w2) from spike bitmasks + cuba3 -> out [n][cls][t]
// ---------------------------------------------------------------------------
__global__ __launch_bounds__(256) void snn_fused(
    const float* __restrict__ z2, const float* __restrict__ w1T,
    const float* __restrict__ w2, float* __restrict__ out)
{
    __shared__ float Sc[256 * 16];                 // 16 KB expanded spike chunk
    __shared__ unsigned long long M2[256];         // dense-2 input spike masks
    __shared__ float Y[2 * 63];
    const int n   = blockIdx.x;
    const int tid = threadIdx.x;

    // phase 1: cuba1 on z2[n][t][tid]
    unsigned long long mask = 0ull;
    {
        float cur = 0.f, vol = 0.f;
        const float* zrow = z2 + (size_t)n * 16128 + tid;
        for (int t = 0; t < 63; ++t) {
            float xv = zrow[(size_t)t * 256];
            cur = 0.1f * cur + xv;
            vol = 0.1f * vol + cur;
            float u = vol - 0.3f;
            if (u >= 0.f) { mask |= (1ull << t); vol = 0.f; }
        }
    }

    // phase 2: dense1 + cuba2 (thread = output channel o)
    unsigned long long mask2 = 0ull;
    float v2 = 0.f;
    for (int tc = 0; tc < 4; ++tc) {
        const int T0 = tc * 16;
        __syncthreads();                           // prior chunk reads done
#pragma unroll
        for (int j4 = 0; j4 < 4; ++j4) {
            float4 f;
            f.x = ((mask >> (T0 + j4*4 + 0)) & 1ull) ? 1.f : 0.f;
            f.y = ((mask >> (T0 + j4*4 + 1)) & 1ull) ? 1.f : 0.f;
            f.z = ((mask >> (T0 + j4*4 + 2)) & 1ull) ? 1.f : 0.f;
            f.w = ((mask >> (T0 + j4*4 + 3)) & 1ull) ? 1.f : 0.f;
            *(float4*)&Sc[tid * 16 + j4 * 4] = f;  // canonical stride-16B b128
        }
        __syncthreads();
        float acc[16] = {};
        const float* wp = w1T + tid;               // w1T[c*256 + o], o = tid
#pragma unroll 4
        for (int c = 0; c < 256; ++c) {
            float w = wp[(size_t)c * 256];
            const float* sp = &Sc[c * 16];
#pragma unroll
            for (int j = 0; j < 16; ++j) acc[j] += w * sp[j];
        }
        const int nT = (tc == 3) ? 15 : 16;
        for (int j = 0; j < nT; ++j) {
            v2 = 0.9f * v2 + acc[j];               // cd=0 -> i = x
            float u = v2 - 0.1f;
            if (u >= 0.f) { mask2 |= (1ull << (T0 + j)); v2 = 0.f; }
        }
    }
    __syncthreads();
    M2[tid] = mask2;
    __syncthreads();

    // phase 3: dense2 + cuba3
    if (tid < 126) {
        const int cls = tid / 63;
        const int t   = tid - cls * 63;
        const float* wrow = w2 + cls * 256;
        float acc = 0.f;
#pragma unroll 4
        for (int o = 0; o < 256; ++o)
            acc += ((M2[o] >> t) & 1ull) ? wrow[o] : 0.f;
        Y[cls * 63 + t] = acc;
    }
    __syncthreads();
    if (tid < 2) {
        float v = 0.f;
        float* orow = out + (size_t)n * 126 + tid * 63;
        for (int t = 0; t < 63; ++t) {
            v = 0.9f * v + Y[tid * 63 + t];
            float u = v - 0.1f;
            float s = (u >= 0.f) ? 1.f : 0.f;
            orow[t] = s;
            v = (u >= 0.f) ? 0.f : v;
        }
    }
}

// ---------------------------------------------------------------------------
extern "C" void kernel_launch(void* const* d_in, const int* in_sizes, int n_in,
                              void* d_out, int out_size, void* d_ws, size_t ws_size,
                              hipStream_t stream)
{
    const float* x    = (const float*)d_in[0];
    const float* c1w  = (const float*)d_in[1];
    const float* c1b  = (const float*)d_in[2];
    const float* g1   = (const float*)d_in[3];
    const float* b1   = (const float*)d_in[4];
    const float* m1   = (const float*)d_in[5];
    const float* v1   = (const float*)d_in[6];
    const float* c2w  = (const float*)d_in[7];
    const float* c2b  = (const float*)d_in[8];
    const float* g2   = (const float*)d_in[9];
    const float* b2   = (const float*)d_in[10];
    const float* m2   = (const float*)d_in[11];
    const float* v2   = (const float*)d_in[12];
    const float* w1   = (const float*)d_in[13];
    const float* w2   = (const float*)d_in[14];
    float* out = (float*)d_out;

    float* ws   = (float*)d_ws;
    float* z1   = ws;                      //  8,257,536 floats
    float* z2   = z1 + 8257536;            //  8,257,536
    float* w1T  = z2 + 8257536;            //     65,536
    float* w2cT = w1T + 65536;             //    196,608
    float* ab1  = w2cT + 196608;           //        512
    float* ab2  = ab1 + 512;               //        512  (total ~64 MB)

    prep_kernel<<<256, 256, 0, stream>>>(c1b, g1, b1, m1, v1,
                                         c2w, c2b, g2, b2, m2, v2,
                                         w1, w1T, w2cT, ab1, ab2);
    conv1_gemm<<<dim3(252, 2), 256, 0, stream>>>(x, c1w, ab1, z1);
    conv2_gemm<<<dim3(252, 2), 256, 0, stream>>>(z1, w2cT, ab2, z2);
    snn_fused<<<512, 256, 0, stream>>>(z2, w1T, w2, out);
}